// Round 12
// baseline (322.375 us; speedup 1.0000x reference)
//
#include <hip/hip_runtime.h>

// GCN: h1 = relu(gcnconv(x,W1,b1)); h2 = relu(gcnconv(h1,W2,b2));
// out = sigmoid(mean(h2,0) @ Wf + bf)
// hp = (x@W)*dinv[row], fp8 e4m3, FEATURE-SPLIT into two [n][32] halves (3.2MB each,
// per-XCD-L2-resident). Aggregation = CSR gather, 8 edges/wave (4B/lane), run as
// two half-passes per layer. GEMMs = MFMA 16x16x32 bf16, split-aware epilogue.
// CSR: fixed-slack bucket slots + per-bucket counting sort.

typedef unsigned int u32;
typedef unsigned short u16;
typedef unsigned char u8;
typedef short s16x8 __attribute__((ext_vector_type(8)));
typedef __bf16 bf16x8 __attribute__((ext_vector_type(8)));
typedef float f32x4 __attribute__((ext_vector_type(4)));

constexpr int HID  = 64;
constexpr int SH   = 7;          // dst bucket shift
constexpr int BK   = 128;        // nodes per bucket
constexpr int BPAD = 1024;       // padded bucket count (needs n <= 131072)
constexpr int CH   = 4096;       // edges per partition block
constexpr int SLOT = 5120;       // edge slots per bucket
constexpr int NBLK2 = 4096;      // blocks for fused layer-2 agg + reduce

static __device__ __forceinline__ u8 f2fp8(float f) {
    int p = __builtin_amdgcn_cvt_pk_fp8_f32(f, f, 0, false);
    return (u8)(p & 0xFF);
}
static __device__ __forceinline__ float fp82f(u8 v) {
    return __builtin_amdgcn_cvt_f32_fp8((int)v, 0);
}
static __device__ __forceinline__ u16 f2bf(float f) {
    u32 u = __float_as_uint(f);
    return (u16)((u + 0x7FFFu + ((u >> 16) & 1u)) >> 16);
}

// ---------- init bucket cursors ----------
__global__ void init_bcur_kernel(int* __restrict__ bcur, int B) {
    int b = blockIdx.x * 256 + threadIdx.x;
    if (b < B) bcur[b] = b * SLOT;
}

// ---------- partition: packed (d7<<20|src) into fixed bucket slots ----------
__global__ __launch_bounds__(256) void partition_kernel(const int* __restrict__ src,
                                                        const int* __restrict__ dst,
                                                        int* __restrict__ bcur,
                                                        u32* __restrict__ ep, int ne) {
    __shared__ int hcnt[BPAD];
    __shared__ int hoff[BPAD];
    __shared__ int gbase[BPAD];
    __shared__ u32 stage[CH];
    __shared__ int ssc[256];
    const int t = threadIdx.x;
    const int base = blockIdx.x * CH;
    const int cnt = min(CH, ne - base);
    for (int i = t; i < BPAD; i += 256) hcnt[i] = 0;
    __syncthreads();

    int myr[CH / 256];
    #pragma unroll
    for (int k = 0; k < CH / 256; ++k) {
        int i = t + k * 256;
        if (i < cnt) myr[k] = atomicAdd(&hcnt[dst[base + i] >> SH], 1);
    }
    __syncthreads();
    {
        int c0 = hcnt[t*4], c1 = hcnt[t*4+1], c2 = hcnt[t*4+2], c3 = hcnt[t*4+3];
        int tsum = c0 + c1 + c2 + c3;
        ssc[t] = tsum; __syncthreads();
        int run = tsum;
        for (int off = 1; off < 256; off <<= 1) {
            int v = (t >= off) ? ssc[t - off] : 0;
            __syncthreads();
            run += v; ssc[t] = run;
            __syncthreads();
        }
        int ex = run - tsum;
        hoff[t*4] = ex; ex += c0;
        hoff[t*4+1] = ex; ex += c1;
        hoff[t*4+2] = ex; ex += c2;
        hoff[t*4+3] = ex;
    }
    __syncthreads();
    for (int b = t; b < BPAD; b += 256) {
        int c = hcnt[b];
        if (c) gbase[b] = atomicAdd(&bcur[b], c);
    }
    #pragma unroll
    for (int k = 0; k < CH / 256; ++k) {
        int i = t + k * 256;
        if (i < cnt) {
            int s = src[base + i], d = dst[base + i];
            stage[hoff[d >> SH] + myr[k]] = ((u32)(d & (BK - 1)) << 20) | (u32)s;
        }
    }
    __syncthreads();
    for (int i = t; i < cnt; i += 256) {
        u32 v = stage[i];
        int lo = 0;
        #pragma unroll
        for (int s = 512; s; s >>= 1) {
            int m = lo + s;
            if (m < BPAD && hoff[m] <= i) lo = m;
        }
        ep[gbase[lo] + (i - hoff[lo])] = v;
    }
}

// ---------- per-bucket counting sort -> eidx, rowend, dinv ----------
__global__ __launch_bounds__(256) void bucket_sort_kernel(const u32* __restrict__ ep,
                                                          const int* __restrict__ bcur,
                                                          int* __restrict__ eidx,
                                                          int* __restrict__ rowend,
                                                          float* __restrict__ dinv, int n) {
    __shared__ int cnt[BK];
    __shared__ int sc[BK];
    __shared__ int cur[BK];
    const int t = threadIdx.x, b = blockIdx.x;
    const int beg = b * SLOT, end = bcur[b];
    if (t < BK) cnt[t] = 0;
    __syncthreads();
    for (int p = beg + t; p < end; p += 256) atomicAdd(&cnt[ep[p] >> 20], 1);
    __syncthreads();
    if (t < BK) sc[t] = cnt[t];
    __syncthreads();
    for (int o = 1; o < BK; o <<= 1) {
        int v = 0;
        if (t < BK && t >= o) v = sc[t - o];
        __syncthreads();
        if (t < BK) sc[t] += v;
        __syncthreads();
    }
    if (t < BK) {
        int node = b * BK + t;
        if (node < n) {
            rowend[node] = beg + sc[t];
            dinv[node] = rsqrtf((float)cnt[t] + 1.0f);
        }
        cur[t] = beg + sc[t] - cnt[t];
    }
    __syncthreads();
    for (int p = beg + t; p < end; p += 256) {
        u32 v = ep[p];
        int r = atomicAdd(&cur[v >> 20], 1);
        eidx[r] = (int)(v & 0xFFFFFu);
    }
}

// ---------- W pack ----------
template <int K>
__global__ void pack_w_kernel(const float* __restrict__ W, u16* __restrict__ wpack) {
    int i = blockIdx.x * 256 + threadIdx.x;
    if (i >= K * 64) return;
    int e = i & 7, lane = (i >> 3) & 63, nt = (i >> 9) & 3, kk = i >> 11;
    int k = kk * 32 + (lane >> 4) * 8 + e;
    int c = nt * 16 + (lane & 15);
    wpack[i] = f2bf(W[k * HID + c]);
}

// ---------- MFMA GEMM with split fp8 I/O ----------
// f32 input: A contiguous [n][K]. fp8 input: A = half0 [n][32], A2 = half1 [n][32].
// Output split: outA = cols 0..31, outB = cols 32..63.
template <int K, typename TIn>
__global__ __launch_bounds__(256) void mfma_gemm_kernel(const TIn* __restrict__ A,
                                                        const TIn* __restrict__ A2,
                                                        const u16* __restrict__ wpack,
                                                        const float* __restrict__ dinv,
                                                        u8* __restrict__ outA,
                                                        u8* __restrict__ outB, int n) {
    const int t = threadIdx.x;
    const int lane = t & 63;
    const int wid = t >> 6;
    const int r16 = lane & 15;
    const int kgrp = lane >> 4;
    const int ntiles = (n + 15) >> 4;
    for (int tile = blockIdx.x * 4 + wid; tile < ntiles; tile += gridDim.x * 4) {
        const int row0 = tile * 16;
        const int arow = row0 + r16;
        f32x4 acc[4] = {f32x4{0,0,0,0}, f32x4{0,0,0,0}, f32x4{0,0,0,0}, f32x4{0,0,0,0}};
        #pragma unroll
        for (int kk = 0; kk < K / 32; ++kk) {
            s16x8 abits;
            if constexpr (sizeof(TIn) == 4) {
                const float* Af = (const float*)A;
                if (arow < n) {
                    const float4* p0 = (const float4*)(Af + (size_t)arow * K + kk * 32 + kgrp * 8);
                    float4 v0 = p0[0], v1 = p0[1];
                    abits[0] = (short)f2bf(v0.x); abits[1] = (short)f2bf(v0.y);
                    abits[2] = (short)f2bf(v0.z); abits[3] = (short)f2bf(v0.w);
                    abits[4] = (short)f2bf(v1.x); abits[5] = (short)f2bf(v1.y);
                    abits[6] = (short)f2bf(v1.z); abits[7] = (short)f2bf(v1.w);
                } else {
                    #pragma unroll
                    for (int j = 0; j < 8; ++j) abits[j] = 0;
                }
            } else {
                const u8* src = (kk == 0) ? (const u8*)A : (const u8*)A2;
                u32 w0 = 0, w1 = 0;
                if (arow < n) {
                    const u32* p0 = (const u32*)(src + (size_t)arow * 32 + kgrp * 8);
                    w0 = p0[0]; w1 = p0[1];
                }
                abits[0] = (short)f2bf(__builtin_amdgcn_cvt_f32_fp8((int)w0, 0));
                abits[1] = (short)f2bf(__builtin_amdgcn_cvt_f32_fp8((int)w0, 1));
                abits[2] = (short)f2bf(__builtin_amdgcn_cvt_f32_fp8((int)w0, 2));
                abits[3] = (short)f2bf(__builtin_amdgcn_cvt_f32_fp8((int)w0, 3));
                abits[4] = (short)f2bf(__builtin_amdgcn_cvt_f32_fp8((int)w1, 0));
                abits[5] = (short)f2bf(__builtin_amdgcn_cvt_f32_fp8((int)w1, 1));
                abits[6] = (short)f2bf(__builtin_amdgcn_cvt_f32_fp8((int)w1, 2));
                abits[7] = (short)f2bf(__builtin_amdgcn_cvt_f32_fp8((int)w1, 3));
            }
            bf16x8 afrag = __builtin_bit_cast(bf16x8, abits);
            const u16* wp = wpack + ((size_t)(kk * 4) * 64 + lane) * 8;
            #pragma unroll
            for (int nt = 0; nt < 4; ++nt) {
                bf16x8 bfrag = *(const bf16x8*)(wp + (size_t)nt * 64 * 8);
                acc[nt] = __builtin_amdgcn_mfma_f32_16x16x32_bf16(afrag, bfrag, acc[nt], 0, 0, 0);
            }
        }
        #pragma unroll
        for (int reg = 0; reg < 4; ++reg) {
            int r = row0 + kgrp * 4 + reg;
            if (r < n) {
                float dv = dinv[r];
                #pragma unroll
                for (int nt = 0; nt < 4; ++nt) {
                    u8* o = (nt < 2) ? outA : outB;
                    o[(size_t)r * 32 + (nt & 1) * 16 + r16] = f2fp8(acc[nt][reg] * dv);
                }
            }
        }
    }
}

#define CVT4(acc0, acc1, acc2, acc3, wv) \
    acc0 += __builtin_amdgcn_cvt_f32_fp8((int)(wv), 0); \
    acc1 += __builtin_amdgcn_cvt_f32_fp8((int)(wv), 1); \
    acc2 += __builtin_amdgcn_cvt_f32_fp8((int)(wv), 2); \
    acc3 += __builtin_amdgcn_cvt_f32_fp8((int)(wv), 3);

// ---------- half-pass CSR gather (layer 1): 8 edges/wave, 32B rows ----------
// g = lane>>3 (edge slot 0..7), fb = lane&7 (feature block of 4 within half)
__global__ __launch_bounds__(256) void agg_half_kernel(const u8* __restrict__ hpH,
                                                       const int* __restrict__ eidx,
                                                       const int* __restrict__ rowend,
                                                       const float* __restrict__ dinv,
                                                       const float* __restrict__ biasH,
                                                       u8* __restrict__ outH, int n) {
    int w = (blockIdx.x * 256 + threadIdx.x) >> 6;
    int lane = threadIdx.x & 63;
    if (w >= n) return;
    const int g = lane >> 3, fb = lane & 7;
    int beg = (w & (BK - 1)) ? rowend[w - 1] : (w >> SH) * SLOT;
    int end = rowend[w];
    float a0 = 0.f, a1 = 0.f, a2 = 0.f, a3 = 0.f;
    int p = beg;
    for (; p + 32 <= end; p += 32) {
        int s[4];
        #pragma unroll
        for (int j = 0; j < 4; ++j) s[j] = __builtin_nontemporal_load(eidx + p + j * 8 + g);
        u32 wv[4];
        #pragma unroll
        for (int j = 0; j < 4; ++j) wv[j] = *(const u32*)(hpH + (size_t)s[j] * 32 + fb * 4);
        #pragma unroll
        for (int j = 0; j < 4; ++j) { CVT4(a0, a1, a2, a3, wv[j]) }
    }
    for (; p < end; p += 8) {
        int idx = p + g;
        bool valid = idx < end;
        int s = __builtin_nontemporal_load(eidx + (valid ? idx : beg));
        u32 wv = *(const u32*)(hpH + (size_t)s * 32 + fb * 4);
        if (valid) { CVT4(a0, a1, a2, a3, wv) }
    }
    a0 += __shfl_xor(a0, 8); a0 += __shfl_xor(a0, 16); a0 += __shfl_xor(a0, 32);
    a1 += __shfl_xor(a1, 8); a1 += __shfl_xor(a1, 16); a1 += __shfl_xor(a1, 32);
    a2 += __shfl_xor(a2, 8); a2 += __shfl_xor(a2, 16); a2 += __shfl_xor(a2, 32);
    a3 += __shfl_xor(a3, 8); a3 += __shfl_xor(a3, 16); a3 += __shfl_xor(a3, 32);
    u32 sv = *(const u32*)(hpH + (size_t)w * 32 + fb * 4);
    float dv = dinv[w];
    float v0 = fmaxf(dv * (a0 + __builtin_amdgcn_cvt_f32_fp8((int)sv, 0)) + biasH[fb * 4 + 0], 0.f);
    float v1 = fmaxf(dv * (a1 + __builtin_amdgcn_cvt_f32_fp8((int)sv, 1)) + biasH[fb * 4 + 1], 0.f);
    float v2 = fmaxf(dv * (a2 + __builtin_amdgcn_cvt_f32_fp8((int)sv, 2)) + biasH[fb * 4 + 2], 0.f);
    float v3 = fmaxf(dv * (a3 + __builtin_amdgcn_cvt_f32_fp8((int)sv, 3)) + biasH[fb * 4 + 3], 0.f);
    if (g == 0) {
        int r = __builtin_amdgcn_cvt_pk_fp8_f32(v0, v1, 0, false);
        r = __builtin_amdgcn_cvt_pk_fp8_f32(v2, v3, r, true);
        __builtin_nontemporal_store((u32)r, (u32*)(outH + (size_t)w * 32 + fb * 4));
    }
}

// ---------- half-pass layer-2 aggregation fused with graph-mean partials ----------
__global__ __launch_bounds__(256) void agg_reduce_half_kernel(const u8* __restrict__ hpH,
                                                              const int* __restrict__ eidx,
                                                              const int* __restrict__ rowend,
                                                              const float* __restrict__ dinv,
                                                              const float* __restrict__ biasH,
                                                              float* __restrict__ partialsH, int n) {
    __shared__ float sred[128];
    int t = threadIdx.x, lane = t & 63;
    const int g = lane >> 3, fb = lane & 7;
    int wid = (blockIdx.x * 256 + t) >> 6;
    int wstride = gridDim.x * 4;
    float bl0 = biasH[fb * 4 + 0], bl1 = biasH[fb * 4 + 1];
    float bl2 = biasH[fb * 4 + 2], bl3 = biasH[fb * 4 + 3];
    float t0 = 0.f, t1 = 0.f, t2 = 0.f, t3 = 0.f;
    for (int w = wid; w < n; w += wstride) {
        int beg = (w & (BK - 1)) ? rowend[w - 1] : (w >> SH) * SLOT;
        int end = rowend[w];
        float a0 = 0.f, a1 = 0.f, a2 = 0.f, a3 = 0.f;
        int p = beg;
        for (; p + 32 <= end; p += 32) {
            int s[4];
            #pragma unroll
            for (int j = 0; j < 4; ++j) s[j] = __builtin_nontemporal_load(eidx + p + j * 8 + g);
            u32 wv[4];
            #pragma unroll
            for (int j = 0; j < 4; ++j) wv[j] = *(const u32*)(hpH + (size_t)s[j] * 32 + fb * 4);
            #pragma unroll
            for (int j = 0; j < 4; ++j) { CVT4(a0, a1, a2, a3, wv[j]) }
        }
        for (; p < end; p += 8) {
            int idx = p + g;
            bool valid = idx < end;
            int s = __builtin_nontemporal_load(eidx + (valid ? idx : beg));
            u32 wv = *(const u32*)(hpH + (size_t)s * 32 + fb * 4);
            if (valid) { CVT4(a0, a1, a2, a3, wv) }
        }
        a0 += __shfl_xor(a0, 8); a0 += __shfl_xor(a0, 16); a0 += __shfl_xor(a0, 32);
        a1 += __shfl_xor(a1, 8); a1 += __shfl_xor(a1, 16); a1 += __shfl_xor(a1, 32);
        a2 += __shfl_xor(a2, 8); a2 += __shfl_xor(a2, 16); a2 += __shfl_xor(a2, 32);
        a3 += __shfl_xor(a3, 8); a3 += __shfl_xor(a3, 16); a3 += __shfl_xor(a3, 32);
        u32 sv = *(const u32*)(hpH + (size_t)w * 32 + fb * 4);
        float dv = dinv[w];
        t0 += fmaxf(dv * (a0 + __builtin_amdgcn_cvt_f32_fp8((int)sv, 0)) + bl0, 0.f);
        t1 += fmaxf(dv * (a1 + __builtin_amdgcn_cvt_f32_fp8((int)sv, 1)) + bl1, 0.f);
        t2 += fmaxf(dv * (a2 + __builtin_amdgcn_cvt_f32_fp8((int)sv, 2)) + bl2, 0.f);
        t3 += fmaxf(dv * (a3 + __builtin_amdgcn_cvt_f32_fp8((int)sv, 3)) + bl3, 0.f);
    }
    int wv_ = t >> 6;
    if (g == 0) {
        sred[wv_ * 32 + fb * 4 + 0] = t0;
        sred[wv_ * 32 + fb * 4 + 1] = t1;
        sred[wv_ * 32 + fb * 4 + 2] = t2;
        sred[wv_ * 32 + fb * 4 + 3] = t3;
    }
    __syncthreads();
    if (t < 32) partialsH[blockIdx.x * 32 + t] = sred[t] + sred[t + 32] + sred[t + 64] + sred[t + 96];
}

// ---------- partial reduction over both halves ----------
__global__ __launch_bounds__(256) void gsum_stage_kernel(const float* __restrict__ partsA,
                                                         const float* __restrict__ partsB, int nblk,
                                                         float* __restrict__ gsum) {
    __shared__ float sred[256];
    int t = threadIdx.x, col = t & 63;
    const float* ps = (col < 32) ? partsA : partsB;
    int c32 = col & 31;
    float a = 0.f;
    for (int bk = blockIdx.x * 4 + (t >> 6); bk < nblk; bk += gridDim.x * 4)
        a += ps[bk * 32 + c32];
    sred[t] = a; __syncthreads();
    if (t < 64) atomicAdd(&gsum[t], sred[t] + sred[t + 64] + sred[t + 128] + sred[t + 192]);
}

__global__ void final_gsum_kernel(const float* __restrict__ gsum, const float* __restrict__ Wf,
                                  const float* __restrict__ bf_, float* __restrict__ out, float invn) {
    int lane = threadIdx.x;
    float v = gsum[lane] * invn * Wf[lane];
    #pragma unroll
    for (int off = 32; off; off >>= 1) v += __shfl_down(v, off);
    if (lane == 0) out[0] = 1.f / (1.f + expf(-(v + bf_[0])));
}

// ================= fallback (atomic aggregation, fp8 hp contiguous, VALU gemm) =================
template <int K, typename TIn>
__global__ __launch_bounds__(256) void gemm_scale_kernel(const TIn* __restrict__ A,
                                                         const float* __restrict__ W,
                                                         const float* __restrict__ dinv,
                                                         u8* __restrict__ out8, int n) {
    __shared__ float xs[16][K];
    const int t = threadIdx.x;
    const int row0 = blockIdx.x * 16;
    if constexpr (sizeof(TIn) == 4) {
        const float* Af = (const float*)A;
        for (int i = t; i < 16 * K; i += 256) {
            int r = i / K;
            (&xs[0][0])[i] = (row0 + r < n) ? Af[(size_t)row0 * K + i] : 0.f;
        }
    } else {
        const u8* Ab = (const u8*)A;
        for (int i = t; i < 16 * K; i += 256) {
            int r = i / K;
            (&xs[0][0])[i] = (row0 + r < n) ? fp82f(Ab[(size_t)row0 * K + i]) : 0.f;
        }
    }
    __syncthreads();
    const int c = t & 63, rg = t >> 6;
    float acc[4] = {0.f, 0.f, 0.f, 0.f};
    #pragma unroll 4
    for (int k = 0; k < K; ++k) {
        float w = W[k * HID + c];
        #pragma unroll
        for (int j = 0; j < 4; ++j) acc[j] += xs[rg + 4 * j][k] * w;
    }
    #pragma unroll
    for (int j = 0; j < 4; ++j) {
        int r = row0 + rg + 4 * j;
        if (r < n) out8[(size_t)r * HID + c] = f2fp8(acc[j] * dinv[r]);
    }
}
__global__ void deg_f_kernel(const int* __restrict__ dst, float* __restrict__ deg, int ne) {
    int i = blockIdx.x * blockDim.x + threadIdx.x, st = gridDim.x * blockDim.x;
    for (; i < ne; i += st) atomicAdd(&deg[dst[i]], 1.0f);
}
__global__ void dinvf_kernel(float* __restrict__ deg, int n) {
    int i = blockIdx.x * blockDim.x + threadIdx.x;
    if (i < n) deg[i] = rsqrtf(deg[i] + 1.0f);
}
__global__ __launch_bounds__(256) void aggregate_atomic_kernel(const u8* __restrict__ hp,
        const int* __restrict__ src, const int* __restrict__ dst,
        const float* __restrict__ dinv, float* __restrict__ outf, int ne) {
    size_t tt = (size_t)blockIdx.x * 256 + threadIdx.x;
    int e = (int)(tt >> 6), f = (int)(tt & 63);
    if (e >= ne) return;
    int s = src[e], d = dst[e];
    atomicAdd(&outf[(size_t)d * HID + f], fp82f(hp[s * HID + f]) * dinv[d]);
}
__global__ void finalize1_fb_kernel(u8* __restrict__ hp, const float* __restrict__ agg,
                                    const float* __restrict__ dinv, const float* __restrict__ b, int n) {
    size_t i = (size_t)blockIdx.x * blockDim.x + threadIdx.x;
    if (i >= (size_t)n * HID) return;
    int node = (int)(i >> 6);
    float v = agg[i] + fp82f(hp[i]) * dinv[node] + b[i & 63];
    hp[i] = f2fp8(fmaxf(v, 0.f));
}
__global__ __launch_bounds__(256) void finalize2_fb_kernel(const u8* __restrict__ hp,
        const float* __restrict__ agg, const float* __restrict__ dinv,
        const float* __restrict__ b, float* __restrict__ gsum, int n) {
    __shared__ float sred[256];
    const int t = threadIdx.x, c = t & 63;
    const size_t total = (size_t)n * HID;
    const size_t stride = (size_t)gridDim.x * blockDim.x;
    float acc = 0.f;
    for (size_t i = (size_t)blockIdx.x * blockDim.x + t; i < total; i += stride) {
        int node = (int)(i >> 6);
        acc += fmaxf(agg[i] + fp82f(hp[i]) * dinv[node] + b[c], 0.f);
    }
    sred[t] = acc; __syncthreads();
    if (t < 64) atomicAdd(&gsum[c], sred[t] + sred[t + 64] + sred[t + 128] + sred[t + 192]);
}
__global__ void final_gsum_fb_kernel(const float* __restrict__ gsum, const float* __restrict__ Wf,
                                     const float* __restrict__ bf_, float* __restrict__ out, int n) {
    int lane = threadIdx.x;
    float v = (gsum[lane] / (float)n) * Wf[lane];
    #pragma unroll
    for (int off = 32; off; off >>= 1) v += __shfl_down(v, off);
    if (lane == 0) out[0] = 1.f / (1.f + expf(-(v + bf_[0])));
}

extern "C" void kernel_launch(void* const* d_in, const int* in_sizes, int n_in,
                              void* d_out, int out_size, void* d_ws, size_t ws_size,
                              hipStream_t stream) {
    const float* x  = (const float*)d_in[0];
    const int*   ei = (const int*)d_in[1];
    const float* W1 = (const float*)d_in[2];
    const float* b1 = (const float*)d_in[3];
    const float* W2 = (const float*)d_in[4];
    const float* b2 = (const float*)d_in[5];
    const float* Wf = (const float*)d_in[6];
    const float* bf_ = (const float*)d_in[7];
    float* out = (float*)d_out;

    const int n  = in_sizes[0] / 256;
    const int ne = in_sizes[1] / 2;
    const int* srcp = ei;
    const int* dstp = ei + ne;
    const int B = (n + BK - 1) / BK;

    // ---- primary layout ----
    char* p = (char*)d_ws;
    u32*   ep     = (u32*)p;   p += ((size_t)B * SLOT + 4096) * 4;
    int*   bcur   = (int*)p;   p += BPAD * 4;
    float* dinv   = (float*)p; p += (size_t)n * 4;
    int*   rowend = (int*)p;   p += (size_t)n * 4;
    float* gsum   = (float*)p; p += 64 * 4;
    int*   eidx   = (int*)p;   p += ((size_t)B * SLOT + 4096) * 4;
    float* partsA = (float*)p; p += (size_t)NBLK2 * 32 * 4;
    float* partsB = (float*)p; p += (size_t)NBLK2 * 32 * 4;
    p = (char*)(((uintptr_t)p + 15) & ~(uintptr_t)15);
    u16*   wpack1 = (u16*)p;   p += 256 * 64 * 2;
    u16*   wpack2 = (u16*)p;   p += 64 * 64 * 2;
    u8*    hpA    = (u8*)p;    p += (size_t)n * 32;
    u8*    hpB    = (u8*)p;    p += (size_t)n * 32;
    u8*    h1A    = (u8*)p;    p += (size_t)n * 32;
    u8*    h1B    = (u8*)p;    p += (size_t)n * 32;
    size_t need = (size_t)(p - (char*)d_ws);

    bool slack_ok = ((size_t)ne / (size_t)B) <= (size_t)(SLOT - 1024);

    if (ws_size >= need && n <= (1 << 17) && slack_ok) {
        (void)hipMemsetAsync(gsum, 0, 64 * 4, stream);
        init_bcur_kernel<<<(B + 255) / 256, 256, 0, stream>>>(bcur, B);
        partition_kernel<<<(ne + CH - 1) / CH, 256, 0, stream>>>(srcp, dstp, bcur, ep, ne);
        bucket_sort_kernel<<<B, 256, 0, stream>>>(ep, bcur, eidx, rowend, dinv, n);
        pack_w_kernel<256><<<64, 256, 0, stream>>>(W1, wpack1);
        pack_w_kernel<64><<<16, 256, 0, stream>>>(W2, wpack2);

        const int ntiles = (n + 15) / 16;
        const int gblk = (ntiles + 3) / 4;
        const int ablk = (n + 3) / 4;
        // layer 1
        mfma_gemm_kernel<256, float><<<gblk, 256, 0, stream>>>(x, nullptr, wpack1, dinv, hpA, hpB, n);
        agg_half_kernel<<<ablk, 256, 0, stream>>>(hpA, eidx, rowend, dinv, b1, h1A, n);
        agg_half_kernel<<<ablk, 256, 0, stream>>>(hpB, eidx, rowend, dinv, b1 + 32, h1B, n);
        // layer 2
        mfma_gemm_kernel<64, u8><<<gblk, 256, 0, stream>>>(h1A, h1B, wpack2, dinv, hpA, hpB, n);
        agg_reduce_half_kernel<<<NBLK2, 256, 0, stream>>>(hpA, eidx, rowend, dinv, b2, partsA, n);
        agg_reduce_half_kernel<<<NBLK2, 256, 0, stream>>>(hpB, eidx, rowend, dinv, b2 + 32, partsB, n);
        gsum_stage_kernel<<<128, 256, 0, stream>>>(partsA, partsB, NBLK2, gsum);
        final_gsum_kernel<<<1, 64, 0, stream>>>(gsum, Wf, bf_, out, 1.0f / (float)n);
    } else {
        // ---- fallback: atomic aggregation, fp8 hp, VALU gemm ----
        char* q = (char*)d_ws;
        float* dinvF = (float*)q; q += (size_t)n * 4;
        float* gsumF = (float*)q; q += 64 * 4;
        u8*    hpF   = (u8*)q;   q += (size_t)n * HID;
        float* aggF  = (float*)q;

        (void)hipMemsetAsync(dinvF, 0, ((size_t)n + 64) * 4, stream);
        deg_f_kernel<<<2048, 256, 0, stream>>>(dstp, dinvF, ne);
        dinvf_kernel<<<(n + 255) / 256, 256, 0, stream>>>(dinvF, n);

        gemm_scale_kernel<256, float><<<(n + 15) / 16, 256, 0, stream>>>(x, W1, dinvF, hpF, n);
        (void)hipMemsetAsync(aggF, 0, (size_t)n * HID * 4, stream);
        aggregate_atomic_kernel<<<(int)(((size_t)ne * 64 + 255) / 256), 256, 0, stream>>>(hpF, srcp, dstp, dinvF, aggF, ne);
        finalize1_fb_kernel<<<(int)(((size_t)n * HID + 255) / 256), 256, 0, stream>>>(hpF, aggF, dinvF, b1, n);

        gemm_scale_kernel<64, u8><<<(n + 15) / 16, 256, 0, stream>>>(hpF, W2, dinvF, hpF, n);
        (void)hipMemsetAsync(aggF, 0, (size_t)n * HID * 4, stream);
        aggregate_atomic_kernel<<<(int)(((size_t)ne * 64 + 255) / 256), 256, 0, stream>>>(hpF, srcp, dstp, dinvF, aggF, ne);
        finalize2_fb_kernel<<<2048, 256, 0, stream>>>(hpF, aggF, dinvF, b2, gsumF, n);
        final_gsum_fb_kernel<<<1, 64, 0, stream>>>(gsumF, Wf, bf_, out, n);
    }
}

// Round 13
// 258.570 us; speedup vs baseline: 1.2468x; 1.2468x over previous
//
#include <hip/hip_runtime.h>

// GCN: h1 = relu(gcnconv(x,W1,b1)); h2 = relu(gcnconv(h1,W2,b2));
// out = sigmoid(mean(h2,0) @ Wf + bf)
// hp = (x@W)*dinv[row] stored fp8 e4m3 [n][64]; aggregation = CSR gather,
// 4 edges per wave (4B/lane), 16-edge unroll + NT index loads.
// GEMMs = MFMA 16x16x32 bf16; CSR: fixed-slack bucket slots + counting sort.

typedef unsigned int u32;
typedef unsigned short u16;
typedef unsigned char u8;
typedef short s16x8 __attribute__((ext_vector_type(8)));
typedef __bf16 bf16x8 __attribute__((ext_vector_type(8)));
typedef float f32x4 __attribute__((ext_vector_type(4)));

constexpr int HID  = 64;
constexpr int SH   = 7;          // dst bucket shift
constexpr int BK   = 128;        // nodes per bucket
constexpr int BPAD = 1024;       // padded bucket count (needs n <= 131072)
constexpr int CH   = 4096;       // edges per partition block
constexpr int SLOT = 5120;       // edge slots per bucket
constexpr int NBLK2 = 4096;      // blocks for fused layer-2 agg + reduce

static __device__ __forceinline__ u8 f2fp8(float f) {
    int p = __builtin_amdgcn_cvt_pk_fp8_f32(f, f, 0, false);
    return (u8)(p & 0xFF);
}
static __device__ __forceinline__ float fp82f(u8 v) {
    return __builtin_amdgcn_cvt_f32_fp8((int)v, 0);
}
static __device__ __forceinline__ u16 f2bf(float f) {
    u32 u = __float_as_uint(f);
    return (u16)((u + 0x7FFFu + ((u >> 16) & 1u)) >> 16);
}

// ---------- init bucket cursors ----------
__global__ void init_bcur_kernel(int* __restrict__ bcur, int B) {
    int b = blockIdx.x * 256 + threadIdx.x;
    if (b < B) bcur[b] = b * SLOT;
}

// ---------- partition: packed (d7<<20|src) into fixed bucket slots ----------
__global__ __launch_bounds__(256) void partition_kernel(const int* __restrict__ src,
                                                        const int* __restrict__ dst,
                                                        int* __restrict__ bcur,
                                                        u32* __restrict__ ep, int ne) {
    __shared__ int hcnt[BPAD];
    __shared__ int hoff[BPAD];
    __shared__ int gbase[BPAD];
    __shared__ u32 stage[CH];
    __shared__ int ssc[256];
    const int t = threadIdx.x;
    const int base = blockIdx.x * CH;
    const int cnt = min(CH, ne - base);
    for (int i = t; i < BPAD; i += 256) hcnt[i] = 0;
    __syncthreads();

    int myr[CH / 256];
    #pragma unroll
    for (int k = 0; k < CH / 256; ++k) {
        int i = t + k * 256;
        if (i < cnt) myr[k] = atomicAdd(&hcnt[dst[base + i] >> SH], 1);
    }
    __syncthreads();
    {
        int c0 = hcnt[t*4], c1 = hcnt[t*4+1], c2 = hcnt[t*4+2], c3 = hcnt[t*4+3];
        int tsum = c0 + c1 + c2 + c3;
        ssc[t] = tsum; __syncthreads();
        int run = tsum;
        for (int off = 1; off < 256; off <<= 1) {
            int v = (t >= off) ? ssc[t - off] : 0;
            __syncthreads();
            run += v; ssc[t] = run;
            __syncthreads();
        }
        int ex = run - tsum;
        hoff[t*4] = ex; ex += c0;
        hoff[t*4+1] = ex; ex += c1;
        hoff[t*4+2] = ex; ex += c2;
        hoff[t*4+3] = ex;
    }
    __syncthreads();
    for (int b = t; b < BPAD; b += 256) {
        int c = hcnt[b];
        if (c) gbase[b] = atomicAdd(&bcur[b], c);
    }
    #pragma unroll
    for (int k = 0; k < CH / 256; ++k) {
        int i = t + k * 256;
        if (i < cnt) {
            int s = src[base + i], d = dst[base + i];
            stage[hoff[d >> SH] + myr[k]] = ((u32)(d & (BK - 1)) << 20) | (u32)s;
        }
    }
    __syncthreads();
    for (int i = t; i < cnt; i += 256) {
        u32 v = stage[i];
        int lo = 0;
        #pragma unroll
        for (int s = 512; s; s >>= 1) {
            int m = lo + s;
            if (m < BPAD && hoff[m] <= i) lo = m;
        }
        ep[gbase[lo] + (i - hoff[lo])] = v;
    }
}

// ---------- per-bucket counting sort -> eidx, rowend, dinv ----------
__global__ __launch_bounds__(256) void bucket_sort_kernel(const u32* __restrict__ ep,
                                                          const int* __restrict__ bcur,
                                                          int* __restrict__ eidx,
                                                          int* __restrict__ rowend,
                                                          float* __restrict__ dinv, int n) {
    __shared__ int cnt[BK];
    __shared__ int sc[BK];
    __shared__ int cur[BK];
    const int t = threadIdx.x, b = blockIdx.x;
    const int beg = b * SLOT, end = bcur[b];
    if (t < BK) cnt[t] = 0;
    __syncthreads();
    for (int p = beg + t; p < end; p += 256) atomicAdd(&cnt[ep[p] >> 20], 1);
    __syncthreads();
    if (t < BK) sc[t] = cnt[t];
    __syncthreads();
    for (int o = 1; o < BK; o <<= 1) {
        int v = 0;
        if (t < BK && t >= o) v = sc[t - o];
        __syncthreads();
        if (t < BK) sc[t] += v;
        __syncthreads();
    }
    if (t < BK) {
        int node = b * BK + t;
        if (node < n) {
            rowend[node] = beg + sc[t];
            dinv[node] = rsqrtf((float)cnt[t] + 1.0f);
        }
        cur[t] = beg + sc[t] - cnt[t];
    }
    __syncthreads();
    for (int p = beg + t; p < end; p += 256) {
        u32 v = ep[p];
        int r = atomicAdd(&cur[v >> 20], 1);
        eidx[r] = (int)(v & 0xFFFFFu);
    }
}

// ---------- W pack ----------
template <int K>
__global__ void pack_w_kernel(const float* __restrict__ W, u16* __restrict__ wpack) {
    int i = blockIdx.x * 256 + threadIdx.x;
    if (i >= K * 64) return;
    int e = i & 7, lane = (i >> 3) & 63, nt = (i >> 9) & 3, kk = i >> 11;
    int k = kk * 32 + (lane >> 4) * 8 + e;
    int c = nt * 16 + (lane & 15);
    wpack[i] = f2bf(W[k * HID + c]);
}

// ---------- MFMA GEMM: out8[r][c] = fp8( (A[r,:]@W[:,c]) * dinv[r] ) ----------
template <int K, typename TIn>
__global__ __launch_bounds__(256) void mfma_gemm_kernel(const TIn* __restrict__ A,
                                                        const u16* __restrict__ wpack,
                                                        const float* __restrict__ dinv,
                                                        u8* __restrict__ out8, int n) {
    const int t = threadIdx.x;
    const int lane = t & 63;
    const int wid = t >> 6;
    const int r16 = lane & 15;
    const int kgrp = lane >> 4;
    const int ntiles = (n + 15) >> 4;
    for (int tile = blockIdx.x * 4 + wid; tile < ntiles; tile += gridDim.x * 4) {
        const int row0 = tile * 16;
        const int arow = row0 + r16;
        f32x4 acc[4] = {f32x4{0,0,0,0}, f32x4{0,0,0,0}, f32x4{0,0,0,0}, f32x4{0,0,0,0}};
        #pragma unroll
        for (int kk = 0; kk < K / 32; ++kk) {
            s16x8 abits;
            if constexpr (sizeof(TIn) == 4) {
                const float* Af = (const float*)A;
                if (arow < n) {
                    const float4* p0 = (const float4*)(Af + (size_t)arow * K + kk * 32 + kgrp * 8);
                    float4 v0 = p0[0], v1 = p0[1];
                    abits[0] = (short)f2bf(v0.x); abits[1] = (short)f2bf(v0.y);
                    abits[2] = (short)f2bf(v0.z); abits[3] = (short)f2bf(v0.w);
                    abits[4] = (short)f2bf(v1.x); abits[5] = (short)f2bf(v1.y);
                    abits[6] = (short)f2bf(v1.z); abits[7] = (short)f2bf(v1.w);
                } else {
                    #pragma unroll
                    for (int j = 0; j < 8; ++j) abits[j] = 0;
                }
            } else {
                const u8* Ab = (const u8*)A;
                u32 w0 = 0, w1 = 0;
                if (arow < n) {
                    const u32* p0 = (const u32*)(Ab + (size_t)arow * K + kk * 32 + kgrp * 8);
                    w0 = p0[0]; w1 = p0[1];
                }
                abits[0] = (short)f2bf(__builtin_amdgcn_cvt_f32_fp8((int)w0, 0));
                abits[1] = (short)f2bf(__builtin_amdgcn_cvt_f32_fp8((int)w0, 1));
                abits[2] = (short)f2bf(__builtin_amdgcn_cvt_f32_fp8((int)w0, 2));
                abits[3] = (short)f2bf(__builtin_amdgcn_cvt_f32_fp8((int)w0, 3));
                abits[4] = (short)f2bf(__builtin_amdgcn_cvt_f32_fp8((int)w1, 0));
                abits[5] = (short)f2bf(__builtin_amdgcn_cvt_f32_fp8((int)w1, 1));
                abits[6] = (short)f2bf(__builtin_amdgcn_cvt_f32_fp8((int)w1, 2));
                abits[7] = (short)f2bf(__builtin_amdgcn_cvt_f32_fp8((int)w1, 3));
            }
            bf16x8 afrag = __builtin_bit_cast(bf16x8, abits);
            const u16* wp = wpack + ((size_t)(kk * 4) * 64 + lane) * 8;
            #pragma unroll
            for (int nt = 0; nt < 4; ++nt) {
                bf16x8 bfrag = *(const bf16x8*)(wp + (size_t)nt * 64 * 8);
                acc[nt] = __builtin_amdgcn_mfma_f32_16x16x32_bf16(afrag, bfrag, acc[nt], 0, 0, 0);
            }
        }
        #pragma unroll
        for (int reg = 0; reg < 4; ++reg) {
            int r = row0 + kgrp * 4 + reg;
            if (r < n) {
                float dv = dinv[r];
                #pragma unroll
                for (int nt = 0; nt < 4; ++nt)
                    out8[(size_t)r * HID + nt * 16 + r16] = f2fp8(acc[nt][reg] * dv);
            }
        }
    }
}

#define CVT4(acc0, acc1, acc2, acc3, wv) \
    acc0 += __builtin_amdgcn_cvt_f32_fp8((int)(wv), 0); \
    acc1 += __builtin_amdgcn_cvt_f32_fp8((int)(wv), 1); \
    acc2 += __builtin_amdgcn_cvt_f32_fp8((int)(wv), 2); \
    acc3 += __builtin_amdgcn_cvt_f32_fp8((int)(wv), 3);

// ---------- CSR gather aggregation, 4 edges/wave (4B/lane), 16-edge unroll + NT ----------
__global__ __launch_bounds__(256) void agg_csr_kernel(const u8* __restrict__ hp,
                                                      const int* __restrict__ eidx,
                                                      const int* __restrict__ rowend,
                                                      const float* __restrict__ dinv,
                                                      const float* __restrict__ bias,
                                                      u8* __restrict__ out, int n) {
    int w = (blockIdx.x * 256 + threadIdx.x) >> 6;
    int lane = threadIdx.x & 63;
    if (w >= n) return;
    const int g = lane >> 4, fb = lane & 15;
    int beg = (w & (BK - 1)) ? rowend[w - 1] : (w >> SH) * SLOT;
    int end = rowend[w];
    float a0 = 0.f, a1 = 0.f, a2 = 0.f, a3 = 0.f;
    int p = beg;
    for (; p + 16 <= end; p += 16) {
        int s0 = __builtin_nontemporal_load(eidx + p + g);
        int s1 = __builtin_nontemporal_load(eidx + p + 4 + g);
        int s2 = __builtin_nontemporal_load(eidx + p + 8 + g);
        int s3 = __builtin_nontemporal_load(eidx + p + 12 + g);
        u32 w0 = *(const u32*)(hp + (size_t)s0 * 64 + fb * 4);
        u32 w1 = *(const u32*)(hp + (size_t)s1 * 64 + fb * 4);
        u32 w2 = *(const u32*)(hp + (size_t)s2 * 64 + fb * 4);
        u32 w3 = *(const u32*)(hp + (size_t)s3 * 64 + fb * 4);
        CVT4(a0, a1, a2, a3, w0)
        CVT4(a0, a1, a2, a3, w1)
        CVT4(a0, a1, a2, a3, w2)
        CVT4(a0, a1, a2, a3, w3)
    }
    for (; p < end; p += 4) {
        int idx = p + g;
        bool valid = idx < end;
        int s = __builtin_nontemporal_load(eidx + (valid ? idx : beg));
        u32 wv = *(const u32*)(hp + (size_t)s * 64 + fb * 4);
        if (valid) { CVT4(a0, a1, a2, a3, wv) }
    }
    a0 += __shfl_xor(a0, 16); a0 += __shfl_xor(a0, 32);
    a1 += __shfl_xor(a1, 16); a1 += __shfl_xor(a1, 32);
    a2 += __shfl_xor(a2, 16); a2 += __shfl_xor(a2, 32);
    a3 += __shfl_xor(a3, 16); a3 += __shfl_xor(a3, 32);
    u32 sv = *(const u32*)(hp + (size_t)w * 64 + fb * 4);
    float dv = dinv[w];
    float v0 = fmaxf(dv * (a0 + __builtin_amdgcn_cvt_f32_fp8((int)sv, 0)) + bias[fb * 4 + 0], 0.f);
    float v1 = fmaxf(dv * (a1 + __builtin_amdgcn_cvt_f32_fp8((int)sv, 1)) + bias[fb * 4 + 1], 0.f);
    float v2 = fmaxf(dv * (a2 + __builtin_amdgcn_cvt_f32_fp8((int)sv, 2)) + bias[fb * 4 + 2], 0.f);
    float v3 = fmaxf(dv * (a3 + __builtin_amdgcn_cvt_f32_fp8((int)sv, 3)) + bias[fb * 4 + 3], 0.f);
    if (g == 0) {
        int r = __builtin_amdgcn_cvt_pk_fp8_f32(v0, v1, 0, false);
        r = __builtin_amdgcn_cvt_pk_fp8_f32(v2, v3, r, true);
        *(u32*)(out + (size_t)w * 64 + fb * 4) = (u32)r;
    }
}

// ---------- layer 2: CSR aggregation fused with graph-mean partials ----------
__global__ __launch_bounds__(256) void agg_csr_reduce_kernel(const u8* __restrict__ hp,
                                                             const int* __restrict__ eidx,
                                                             const int* __restrict__ rowend,
                                                             const float* __restrict__ dinv,
                                                             const float* __restrict__ bias,
                                                             float* __restrict__ partials, int n) {
    __shared__ float sred[256];
    int t = threadIdx.x, lane = t & 63;
    const int g = lane >> 4, fb = lane & 15;
    int wid = (blockIdx.x * 256 + t) >> 6;
    int wstride = gridDim.x * 4;
    float bl0 = bias[fb * 4 + 0], bl1 = bias[fb * 4 + 1];
    float bl2 = bias[fb * 4 + 2], bl3 = bias[fb * 4 + 3];
    float t0 = 0.f, t1 = 0.f, t2 = 0.f, t3 = 0.f;
    for (int w = wid; w < n; w += wstride) {
        int beg = (w & (BK - 1)) ? rowend[w - 1] : (w >> SH) * SLOT;
        int end = rowend[w];
        float a0 = 0.f, a1 = 0.f, a2 = 0.f, a3 = 0.f;
        int p = beg;
        for (; p + 16 <= end; p += 16) {
            int s0 = __builtin_nontemporal_load(eidx + p + g);
            int s1 = __builtin_nontemporal_load(eidx + p + 4 + g);
            int s2 = __builtin_nontemporal_load(eidx + p + 8 + g);
            int s3 = __builtin_nontemporal_load(eidx + p + 12 + g);
            u32 w0 = *(const u32*)(hp + (size_t)s0 * 64 + fb * 4);
            u32 w1 = *(const u32*)(hp + (size_t)s1 * 64 + fb * 4);
            u32 w2 = *(const u32*)(hp + (size_t)s2 * 64 + fb * 4);
            u32 w3 = *(const u32*)(hp + (size_t)s3 * 64 + fb * 4);
            CVT4(a0, a1, a2, a3, w0)
            CVT4(a0, a1, a2, a3, w1)
            CVT4(a0, a1, a2, a3, w2)
            CVT4(a0, a1, a2, a3, w3)
        }
        for (; p < end; p += 4) {
            int idx = p + g;
            bool valid = idx < end;
            int s = __builtin_nontemporal_load(eidx + (valid ? idx : beg));
            u32 wv = *(const u32*)(hp + (size_t)s * 64 + fb * 4);
            if (valid) { CVT4(a0, a1, a2, a3, wv) }
        }
        a0 += __shfl_xor(a0, 16); a0 += __shfl_xor(a0, 32);
        a1 += __shfl_xor(a1, 16); a1 += __shfl_xor(a1, 32);
        a2 += __shfl_xor(a2, 16); a2 += __shfl_xor(a2, 32);
        a3 += __shfl_xor(a3, 16); a3 += __shfl_xor(a3, 32);
        u32 sv = *(const u32*)(hp + (size_t)w * 64 + fb * 4);
        float dv = dinv[w];
        t0 += fmaxf(dv * (a0 + __builtin_amdgcn_cvt_f32_fp8((int)sv, 0)) + bl0, 0.f);
        t1 += fmaxf(dv * (a1 + __builtin_amdgcn_cvt_f32_fp8((int)sv, 1)) + bl1, 0.f);
        t2 += fmaxf(dv * (a2 + __builtin_amdgcn_cvt_f32_fp8((int)sv, 2)) + bl2, 0.f);
        t3 += fmaxf(dv * (a3 + __builtin_amdgcn_cvt_f32_fp8((int)sv, 3)) + bl3, 0.f);
    }
    int wv_ = t >> 6;
    if (g == 0) {
        sred[wv_ * 64 + fb * 4 + 0] = t0;
        sred[wv_ * 64 + fb * 4 + 1] = t1;
        sred[wv_ * 64 + fb * 4 + 2] = t2;
        sred[wv_ * 64 + fb * 4 + 3] = t3;
    }
    __syncthreads();
    if (t < 64) partials[blockIdx.x * 64 + t] = sred[t] + sred[t + 64] + sred[t + 128] + sred[t + 192];
}

// ---------- two-stage partial reduction ----------
__global__ __launch_bounds__(256) void gsum_stage_kernel(const float* __restrict__ parts, int nblk,
                                                         float* __restrict__ gsum) {
    __shared__ float sred[256];
    int t = threadIdx.x, col = t & 63;
    float a = 0.f;
    for (int bk = blockIdx.x * 4 + (t >> 6); bk < nblk; bk += gridDim.x * 4)
        a += parts[bk * 64 + col];
    sred[t] = a; __syncthreads();
    if (t < 64) atomicAdd(&gsum[t], sred[t] + sred[t + 64] + sred[t + 128] + sred[t + 192]);
}

__global__ void final_gsum_kernel(const float* __restrict__ gsum, const float* __restrict__ Wf,
                                  const float* __restrict__ bf_, float* __restrict__ out, float invn) {
    int lane = threadIdx.x;
    float v = gsum[lane] * invn * Wf[lane];
    #pragma unroll
    for (int off = 32; off; off >>= 1) v += __shfl_down(v, off);
    if (lane == 0) out[0] = 1.f / (1.f + expf(-(v + bf_[0])));
}

// ================= fallback (atomic aggregation, fp8 hp, VALU gemm) =================
template <int K, typename TIn>
__global__ __launch_bounds__(256) void gemm_scale_kernel(const TIn* __restrict__ A,
                                                         const float* __restrict__ W,
                                                         const float* __restrict__ dinv,
                                                         u8* __restrict__ out8, int n) {
    __shared__ float xs[16][K];
    const int t = threadIdx.x;
    const int row0 = blockIdx.x * 16;
    if constexpr (sizeof(TIn) == 4) {
        const float* Af = (const float*)A;
        for (int i = t; i < 16 * K; i += 256) {
            int r = i / K;
            (&xs[0][0])[i] = (row0 + r < n) ? Af[(size_t)row0 * K + i] : 0.f;
        }
    } else {
        const u8* Ab = (const u8*)A;
        for (int i = t; i < 16 * K; i += 256) {
            int r = i / K;
            (&xs[0][0])[i] = (row0 + r < n) ? fp82f(Ab[(size_t)row0 * K + i]) : 0.f;
        }
    }
    __syncthreads();
    const int c = t & 63, rg = t >> 6;
    float acc[4] = {0.f, 0.f, 0.f, 0.f};
    #pragma unroll 4
    for (int k = 0; k < K; ++k) {
        float w = W[k * HID + c];
        #pragma unroll
        for (int j = 0; j < 4; ++j) acc[j] += xs[rg + 4 * j][k] * w;
    }
    #pragma unroll
    for (int j = 0; j < 4; ++j) {
        int r = row0 + rg + 4 * j;
        if (r < n) out8[(size_t)r * HID + c] = f2fp8(acc[j] * dinv[r]);
    }
}
__global__ void deg_f_kernel(const int* __restrict__ dst, float* __restrict__ deg, int ne) {
    int i = blockIdx.x * blockDim.x + threadIdx.x, st = gridDim.x * blockDim.x;
    for (; i < ne; i += st) atomicAdd(&deg[dst[i]], 1.0f);
}
__global__ void dinvf_kernel(float* __restrict__ deg, int n) {
    int i = blockIdx.x * blockDim.x + threadIdx.x;
    if (i < n) deg[i] = rsqrtf(deg[i] + 1.0f);
}
__global__ __launch_bounds__(256) void aggregate_atomic_kernel(const u8* __restrict__ hp,
        const int* __restrict__ src, const int* __restrict__ dst,
        const float* __restrict__ dinv, float* __restrict__ outf, int ne) {
    size_t tt = (size_t)blockIdx.x * 256 + threadIdx.x;
    int e = (int)(tt >> 6), f = (int)(tt & 63);
    if (e >= ne) return;
    int s = src[e], d = dst[e];
    atomicAdd(&outf[(size_t)d * HID + f], fp82f(hp[s * HID + f]) * dinv[d]);
}
__global__ void finalize1_fb_kernel(u8* __restrict__ hp, const float* __restrict__ agg,
                                    const float* __restrict__ dinv, const float* __restrict__ b, int n) {
    size_t i = (size_t)blockIdx.x * blockDim.x + threadIdx.x;
    if (i >= (size_t)n * HID) return;
    int node = (int)(i >> 6);
    float v = agg[i] + fp82f(hp[i]) * dinv[node] + b[i & 63];
    hp[i] = f2fp8(fmaxf(v, 0.f));
}
__global__ __launch_bounds__(256) void finalize2_fb_kernel(const u8* __restrict__ hp,
        const float* __restrict__ agg, const float* __restrict__ dinv,
        const float* __restrict__ b, float* __restrict__ gsum, int n) {
    __shared__ float sred[256];
    const int t = threadIdx.x, c = t & 63;
    const size_t total = (size_t)n * HID;
    const size_t stride = (size_t)gridDim.x * blockDim.x;
    float acc = 0.f;
    for (size_t i = (size_t)blockIdx.x * blockDim.x + t; i < total; i += stride) {
        int node = (int)(i >> 6);
        acc += fmaxf(agg[i] + fp82f(hp[i]) * dinv[node] + b[c], 0.f);
    }
    sred[t] = acc; __syncthreads();
    if (t < 64) atomicAdd(&gsum[c], sred[t] + sred[t + 64] + sred[t + 128] + sred[t + 192]);
}
__global__ void final_gsum_fb_kernel(const float* __restrict__ gsum, const float* __restrict__ Wf,
                                     const float* __restrict__ bf_, float* __restrict__ out, int n) {
    int lane = threadIdx.x;
    float v = (gsum[lane] / (float)n) * Wf[lane];
    #pragma unroll
    for (int off = 32; off; off >>= 1) v += __shfl_down(v, off);
    if (lane == 0) out[0] = 1.f / (1.f + expf(-(v + bf_[0])));
}

extern "C" void kernel_launch(void* const* d_in, const int* in_sizes, int n_in,
                              void* d_out, int out_size, void* d_ws, size_t ws_size,
                              hipStream_t stream) {
    const float* x  = (const float*)d_in[0];
    const int*   ei = (const int*)d_in[1];
    const float* W1 = (const float*)d_in[2];
    const float* b1 = (const float*)d_in[3];
    const float* W2 = (const float*)d_in[4];
    const float* b2 = (const float*)d_in[5];
    const float* Wf = (const float*)d_in[6];
    const float* bf_ = (const float*)d_in[7];
    float* out = (float*)d_out;

    const int n  = in_sizes[0] / 256;
    const int ne = in_sizes[1] / 2;
    const int* srcp = ei;
    const int* dstp = ei + ne;
    const int B = (n + BK - 1) / BK;

    // ---- primary layout ----
    char* p = (char*)d_ws;
    u32*   ep     = (u32*)p;   p += ((size_t)B * SLOT + 4096) * 4;
    int*   bcur   = (int*)p;   p += BPAD * 4;
    float* dinv   = (float*)p; p += (size_t)n * 4;
    int*   rowend = (int*)p;   p += (size_t)n * 4;
    float* gsum   = (float*)p; p += 64 * 4;
    int*   eidx   = (int*)p;   p += ((size_t)B * SLOT + 4096) * 4;
    float* parts  = (float*)p; p += (size_t)NBLK2 * 64 * 4;
    p = (char*)(((uintptr_t)p + 15) & ~(uintptr_t)15);
    u16*   wpack1 = (u16*)p;   p += 256 * 64 * 2;
    u16*   wpack2 = (u16*)p;   p += 64 * 64 * 2;
    u8*    hp     = (u8*)p;    p += (size_t)n * HID;
    u8*    h1     = (u8*)p;    p += (size_t)n * HID;
    size_t need = (size_t)(p - (char*)d_ws);

    bool slack_ok = ((size_t)ne / (size_t)B) <= (size_t)(SLOT - 1024);

    if (ws_size >= need && n <= (1 << 17) && slack_ok) {
        (void)hipMemsetAsync(gsum, 0, 64 * 4, stream);
        init_bcur_kernel<<<(B + 255) / 256, 256, 0, stream>>>(bcur, B);
        partition_kernel<<<(ne + CH - 1) / CH, 256, 0, stream>>>(srcp, dstp, bcur, ep, ne);
        bucket_sort_kernel<<<B, 256, 0, stream>>>(ep, bcur, eidx, rowend, dinv, n);
        pack_w_kernel<256><<<64, 256, 0, stream>>>(W1, wpack1);
        pack_w_kernel<64><<<16, 256, 0, stream>>>(W2, wpack2);

        const int ntiles = (n + 15) / 16;
        const int gblk = (ntiles + 3) / 4;
        mfma_gemm_kernel<256, float><<<gblk, 256, 0, stream>>>(x, wpack1, dinv, hp, n);
        agg_csr_kernel<<<(n + 3) / 4, 256, 0, stream>>>(hp, eidx, rowend, dinv, b1, h1, n);
        mfma_gemm_kernel<64, u8><<<gblk, 256, 0, stream>>>(h1, wpack2, dinv, hp, n);
        agg_csr_reduce_kernel<<<NBLK2, 256, 0, stream>>>(hp, eidx, rowend, dinv, b2, parts, n);
        gsum_stage_kernel<<<128, 256, 0, stream>>>(parts, NBLK2, gsum);
        final_gsum_kernel<<<1, 64, 0, stream>>>(gsum, Wf, bf_, out, 1.0f / (float)n);
    } else {
        // ---- fallback: atomic aggregation, fp8 hp, VALU gemm ----
        char* q = (char*)d_ws;
        float* dinvF = (float*)q; q += (size_t)n * 4;
        float* gsumF = (float*)q; q += 64 * 4;
        u8*    hpF   = (u8*)q;   q += (size_t)n * HID;
        float* aggF  = (float*)q;

        (void)hipMemsetAsync(dinvF, 0, ((size_t)n + 64) * 4, stream);
        deg_f_kernel<<<2048, 256, 0, stream>>>(dstp, dinvF, ne);
        dinvf_kernel<<<(n + 255) / 256, 256, 0, stream>>>(dinvF, n);

        gemm_scale_kernel<256, float><<<(n + 15) / 16, 256, 0, stream>>>(x, W1, dinvF, hpF, n);
        (void)hipMemsetAsync(aggF, 0, (size_t)n * HID * 4, stream);
        aggregate_atomic_kernel<<<(int)(((size_t)ne * 64 + 255) / 256), 256, 0, stream>>>(hpF, srcp, dstp, dinvF, aggF, ne);
        finalize1_fb_kernel<<<(int)(((size_t)n * HID + 255) / 256), 256, 0, stream>>>(hpF, aggF, dinvF, b1, n);

        gemm_scale_kernel<64, u8><<<(n + 15) / 16, 256, 0, stream>>>(hpF, W2, dinvF, hpF, n);
        (void)hipMemsetAsync(aggF, 0, (size_t)n * HID * 4, stream);
        aggregate_atomic_kernel<<<(int)(((size_t)ne * 64 + 255) / 256), 256, 0, stream>>>(hpF, srcp, dstp, dinvF, aggF, ne);
        finalize2_fb_kernel<<<2048, 256, 0, stream>>>(hpF, aggF, dinvF, b2, gsumF, n);
        final_gsum_fb_kernel<<<1, 64, 0, stream>>>(gsumF, Wf, bf_, out, n);
    }
}

// Round 14
// 248.742 us; speedup vs baseline: 1.2960x; 1.0395x over previous
//
#include <hip/hip_runtime.h>

// GCN: h1 = relu(gcnconv(x,W1,b1)); h2 = relu(gcnconv(h1,W2,b2));
// out = sigmoid(mean(h2,0) @ Wf + bf)
// hp = (x@W)*dinv[row] fp8 e4m3 [n][64]; CSR gather agg (4 edges/wave, 16-unroll, NT).
// MEGA1 fuses partition ∥ gemm1(unscaled); bucket_sort computes dinv AND scales hp.

typedef unsigned int u32;
typedef unsigned short u16;
typedef unsigned char u8;
typedef short s16x8 __attribute__((ext_vector_type(8)));
typedef __bf16 bf16x8 __attribute__((ext_vector_type(8)));
typedef float f32x4 __attribute__((ext_vector_type(4)));

constexpr int HID  = 64;
constexpr int SH   = 7;          // dst bucket shift
constexpr int BK   = 128;        // nodes per bucket
constexpr int BPAD = 1024;       // padded bucket count (needs n <= 131072)
constexpr int CH   = 4096;       // edges per partition block
constexpr int SLOT = 5120;       // edge slots per bucket
constexpr int NBLK2 = 4096;      // blocks for fused layer-2 agg + reduce

static __device__ __forceinline__ u8 f2fp8(float f) {
    int p = __builtin_amdgcn_cvt_pk_fp8_f32(f, f, 0, false);
    return (u8)(p & 0xFF);
}
static __device__ __forceinline__ float fp82f(u8 v) {
    return __builtin_amdgcn_cvt_f32_fp8((int)v, 0);
}
static __device__ __forceinline__ u16 f2bf(float f) {
    u32 u = __float_as_uint(f);
    return (u16)((u + 0x7FFFu + ((u >> 16) & 1u)) >> 16);
}

// ---------- pack W1 and W2 fragments in one kernel ----------
__global__ void pack_both_kernel(const float* __restrict__ W1, const float* __restrict__ W2,
                                 u16* __restrict__ wpack1, u16* __restrict__ wpack2) {
    int i = blockIdx.x * 256 + threadIdx.x;
    if (i < 256 * 64) {
        int e = i & 7, lane = (i >> 3) & 63, nt = (i >> 9) & 3, kk = i >> 11;
        wpack1[i] = f2bf(W1[(kk * 32 + (lane >> 4) * 8 + e) * HID + nt * 16 + (lane & 15)]);
    } else {
        int j = i - 256 * 64;
        if (j < 64 * 64) {
            int e = j & 7, lane = (j >> 3) & 63, nt = (j >> 9) & 3, kk = j >> 11;
            wpack2[j] = f2bf(W2[(kk * 32 + (lane >> 4) * 8 + e) * HID + nt * 16 + (lane & 15)]);
        }
    }
}

// ---------- MEGA1: blocks [0,PBLK) = partition; [PBLK, PBLK+GBLK) = gemm1 (unscaled) ----------
__global__ __launch_bounds__(256) void mega1_kernel(const int* __restrict__ src,
                                                    const int* __restrict__ dst,
                                                    int* __restrict__ bcur,
                                                    u32* __restrict__ ep, int ne,
                                                    const float* __restrict__ x,
                                                    const u16* __restrict__ wpack1,
                                                    u8* __restrict__ hp, int n,
                                                    int PBLK, int GBLK) {
    __shared__ int hcnt[BPAD];
    __shared__ int hoff[BPAD];
    __shared__ int gbase[BPAD];
    __shared__ u32 stage[CH];
    __shared__ int ssc[256];
    const int t = threadIdx.x;

    if ((int)blockIdx.x < PBLK) {
        // ---- partition body ----
        const int base = blockIdx.x * CH;
        const int cnt = min(CH, ne - base);
        for (int i = t; i < BPAD; i += 256) hcnt[i] = 0;
        __syncthreads();
        int myr[CH / 256];
        #pragma unroll
        for (int k = 0; k < CH / 256; ++k) {
            int i = t + k * 256;
            if (i < cnt) myr[k] = atomicAdd(&hcnt[dst[base + i] >> SH], 1);
        }
        __syncthreads();
        {
            int c0 = hcnt[t*4], c1 = hcnt[t*4+1], c2 = hcnt[t*4+2], c3 = hcnt[t*4+3];
            int tsum = c0 + c1 + c2 + c3;
            ssc[t] = tsum; __syncthreads();
            int run = tsum;
            for (int off = 1; off < 256; off <<= 1) {
                int v = (t >= off) ? ssc[t - off] : 0;
                __syncthreads();
                run += v; ssc[t] = run;
                __syncthreads();
            }
            int ex = run - tsum;
            hoff[t*4] = ex; ex += c0;
            hoff[t*4+1] = ex; ex += c1;
            hoff[t*4+2] = ex; ex += c2;
            hoff[t*4+3] = ex;
        }
        __syncthreads();
        for (int b = t; b < BPAD; b += 256) {
            int c = hcnt[b];
            if (c) gbase[b] = b * SLOT + atomicAdd(&bcur[b], c);
        }
        #pragma unroll
        for (int k = 0; k < CH / 256; ++k) {
            int i = t + k * 256;
            if (i < cnt) {
                int s = src[base + i], d = dst[base + i];
                stage[hoff[d >> SH] + myr[k]] = ((u32)(d & (BK - 1)) << 20) | (u32)s;
            }
        }
        __syncthreads();
        for (int i = t; i < cnt; i += 256) {
            u32 v = stage[i];
            int lo = 0;
            #pragma unroll
            for (int s = 512; s; s >>= 1) {
                int m = lo + s;
                if (m < BPAD && hoff[m] <= i) lo = m;
            }
            ep[gbase[lo] + (i - hoff[lo])] = v;
        }
    } else {
        // ---- gemm1 body: hp[r][c] = fp8(x[r,:]@W1[:,c]), UNSCALED ----
        const int gbid = blockIdx.x - PBLK;
        const int lane = t & 63;
        const int wid = t >> 6;
        const int r16 = lane & 15;
        const int kgrp = lane >> 4;
        const int ntiles = (n + 15) >> 4;
        for (int tile = gbid * 4 + wid; tile < ntiles; tile += GBLK * 4) {
            const int row0 = tile * 16;
            const int arow = row0 + r16;
            f32x4 acc[4] = {f32x4{0,0,0,0}, f32x4{0,0,0,0}, f32x4{0,0,0,0}, f32x4{0,0,0,0}};
            #pragma unroll
            for (int kk = 0; kk < 256 / 32; ++kk) {
                s16x8 abits;
                if (arow < n) {
                    const float4* p0 = (const float4*)(x + (size_t)arow * 256 + kk * 32 + kgrp * 8);
                    float4 v0 = p0[0], v1 = p0[1];
                    abits[0] = (short)f2bf(v0.x); abits[1] = (short)f2bf(v0.y);
                    abits[2] = (short)f2bf(v0.z); abits[3] = (short)f2bf(v0.w);
                    abits[4] = (short)f2bf(v1.x); abits[5] = (short)f2bf(v1.y);
                    abits[6] = (short)f2bf(v1.z); abits[7] = (short)f2bf(v1.w);
                } else {
                    #pragma unroll
                    for (int j = 0; j < 8; ++j) abits[j] = 0;
                }
                bf16x8 afrag = __builtin_bit_cast(bf16x8, abits);
                const u16* wp = wpack1 + ((size_t)(kk * 4) * 64 + lane) * 8;
                #pragma unroll
                for (int nt = 0; nt < 4; ++nt) {
                    bf16x8 bfrag = *(const bf16x8*)(wp + (size_t)nt * 64 * 8);
                    acc[nt] = __builtin_amdgcn_mfma_f32_16x16x32_bf16(afrag, bfrag, acc[nt], 0, 0, 0);
                }
            }
            #pragma unroll
            for (int reg = 0; reg < 4; ++reg) {
                int r = row0 + kgrp * 4 + reg;
                if (r < n) {
                    #pragma unroll
                    for (int nt = 0; nt < 4; ++nt)
                        hp[(size_t)r * HID + nt * 16 + r16] = f2fp8(acc[nt][reg]);
                }
            }
        }
    }
}

// ---------- per-bucket counting sort -> eidx, rowend, dinv; scales hp rows by dinv ----------
__global__ __launch_bounds__(256) void bucket_sort_kernel(const u32* __restrict__ ep,
                                                          const int* __restrict__ bcur,
                                                          int* __restrict__ eidx,
                                                          int* __restrict__ rowend,
                                                          float* __restrict__ dinv,
                                                          u8* __restrict__ hp, int n) {
    __shared__ int cnt[BK];
    __shared__ int sc[BK];
    __shared__ int cur[BK];
    __shared__ float sdv[BK];
    const int t = threadIdx.x, b = blockIdx.x;
    const int beg = b * SLOT, end = b * SLOT + bcur[b];
    if (t < BK) cnt[t] = 0;
    __syncthreads();
    for (int p = beg + t; p < end; p += 256) atomicAdd(&cnt[ep[p] >> 20], 1);
    __syncthreads();
    if (t < BK) sc[t] = cnt[t];
    __syncthreads();
    for (int o = 1; o < BK; o <<= 1) {
        int v = 0;
        if (t < BK && t >= o) v = sc[t - o];
        __syncthreads();
        if (t < BK) sc[t] += v;
        __syncthreads();
    }
    if (t < BK) {
        int node = b * BK + t;
        float dv = rsqrtf((float)cnt[t] + 1.0f);
        sdv[t] = dv;
        if (node < n) {
            rowend[node] = beg + sc[t];
            dinv[node] = dv;
        }
        cur[t] = beg + sc[t] - cnt[t];
    }
    __syncthreads();
    for (int p = beg + t; p < end; p += 256) {
        u32 v = ep[p];
        int r = atomicAdd(&cur[v >> 20], 1);
        eidx[r] = (int)(v & 0xFFFFFu);
    }
    // scale this bucket's hp rows by dinv (fp8 -> fp8)
    u32* hp32 = (u32*)hp;
    const int base_node = b * BK;
    for (int i = t; i < BK * 16; i += 256) {
        int r = i >> 4;
        int node = base_node + r;
        if (node < n) {
            size_t off = (size_t)node * 16 + (i & 15);
            u32 v = hp32[off];
            float dv = sdv[r];
            float f0 = __builtin_amdgcn_cvt_f32_fp8((int)v, 0) * dv;
            float f1 = __builtin_amdgcn_cvt_f32_fp8((int)v, 1) * dv;
            float f2 = __builtin_amdgcn_cvt_f32_fp8((int)v, 2) * dv;
            float f3 = __builtin_amdgcn_cvt_f32_fp8((int)v, 3) * dv;
            int pk = __builtin_amdgcn_cvt_pk_fp8_f32(f0, f1, 0, false);
            pk = __builtin_amdgcn_cvt_pk_fp8_f32(f2, f3, pk, true);
            hp32[off] = (u32)pk;
        }
    }
}

// ---------- MFMA GEMM (layer 2): out8[r][c] = fp8( (A[r,:]@W[:,c]) * dinv[r] ) ----------
__global__ __launch_bounds__(256) void mfma_gemm2_kernel(const u8* __restrict__ A,
                                                         const u16* __restrict__ wpack,
                                                         const float* __restrict__ dinv,
                                                         u8* __restrict__ out8, int n) {
    const int t = threadIdx.x;
    const int lane = t & 63;
    const int wid = t >> 6;
    const int r16 = lane & 15;
    const int kgrp = lane >> 4;
    const int ntiles = (n + 15) >> 4;
    for (int tile = blockIdx.x * 4 + wid; tile < ntiles; tile += gridDim.x * 4) {
        const int row0 = tile * 16;
        const int arow = row0 + r16;
        f32x4 acc[4] = {f32x4{0,0,0,0}, f32x4{0,0,0,0}, f32x4{0,0,0,0}, f32x4{0,0,0,0}};
        #pragma unroll
        for (int kk = 0; kk < 2; ++kk) {
            s16x8 abits;
            u32 w0 = 0, w1 = 0;
            if (arow < n) {
                const u32* p0 = (const u32*)(A + (size_t)arow * 64 + kk * 32 + kgrp * 8);
                w0 = p0[0]; w1 = p0[1];
            }
            abits[0] = (short)f2bf(__builtin_amdgcn_cvt_f32_fp8((int)w0, 0));
            abits[1] = (short)f2bf(__builtin_amdgcn_cvt_f32_fp8((int)w0, 1));
            abits[2] = (short)f2bf(__builtin_amdgcn_cvt_f32_fp8((int)w0, 2));
            abits[3] = (short)f2bf(__builtin_amdgcn_cvt_f32_fp8((int)w0, 3));
            abits[4] = (short)f2bf(__builtin_amdgcn_cvt_f32_fp8((int)w1, 0));
            abits[5] = (short)f2bf(__builtin_amdgcn_cvt_f32_fp8((int)w1, 1));
            abits[6] = (short)f2bf(__builtin_amdgcn_cvt_f32_fp8((int)w1, 2));
            abits[7] = (short)f2bf(__builtin_amdgcn_cvt_f32_fp8((int)w1, 3));
            bf16x8 afrag = __builtin_bit_cast(bf16x8, abits);
            const u16* wp = wpack + ((size_t)(kk * 4) * 64 + lane) * 8;
            #pragma unroll
            for (int nt = 0; nt < 4; ++nt) {
                bf16x8 bfrag = *(const bf16x8*)(wp + (size_t)nt * 64 * 8);
                acc[nt] = __builtin_amdgcn_mfma_f32_16x16x32_bf16(afrag, bfrag, acc[nt], 0, 0, 0);
            }
        }
        #pragma unroll
        for (int reg = 0; reg < 4; ++reg) {
            int r = row0 + kgrp * 4 + reg;
            if (r < n) {
                float dv = dinv[r];
                #pragma unroll
                for (int nt = 0; nt < 4; ++nt)
                    out8[(size_t)r * HID + nt * 16 + r16] = f2fp8(acc[nt][reg] * dv);
            }
        }
    }
}

#define CVT4(acc0, acc1, acc2, acc3, wv) \
    acc0 += __builtin_amdgcn_cvt_f32_fp8((int)(wv), 0); \
    acc1 += __builtin_amdgcn_cvt_f32_fp8((int)(wv), 1); \
    acc2 += __builtin_amdgcn_cvt_f32_fp8((int)(wv), 2); \
    acc3 += __builtin_amdgcn_cvt_f32_fp8((int)(wv), 3);

// ---------- CSR gather aggregation, 4 edges/wave, 16-edge unroll + NT ----------
__global__ __launch_bounds__(256) void agg_csr_kernel(const u8* __restrict__ hp,
                                                      const int* __restrict__ eidx,
                                                      const int* __restrict__ rowend,
                                                      const float* __restrict__ dinv,
                                                      const float* __restrict__ bias,
                                                      u8* __restrict__ out, int n) {
    int w = (blockIdx.x * 256 + threadIdx.x) >> 6;
    int lane = threadIdx.x & 63;
    if (w >= n) return;
    const int g = lane >> 4, fb = lane & 15;
    int beg = (w & (BK - 1)) ? rowend[w - 1] : (w >> SH) * SLOT;
    int end = rowend[w];
    float a0 = 0.f, a1 = 0.f, a2 = 0.f, a3 = 0.f;
    int p = beg;
    for (; p + 16 <= end; p += 16) {
        int s0 = __builtin_nontemporal_load(eidx + p + g);
        int s1 = __builtin_nontemporal_load(eidx + p + 4 + g);
        int s2 = __builtin_nontemporal_load(eidx + p + 8 + g);
        int s3 = __builtin_nontemporal_load(eidx + p + 12 + g);
        u32 w0 = *(const u32*)(hp + (size_t)s0 * 64 + fb * 4);
        u32 w1 = *(const u32*)(hp + (size_t)s1 * 64 + fb * 4);
        u32 w2 = *(const u32*)(hp + (size_t)s2 * 64 + fb * 4);
        u32 w3 = *(const u32*)(hp + (size_t)s3 * 64 + fb * 4);
        CVT4(a0, a1, a2, a3, w0)
        CVT4(a0, a1, a2, a3, w1)
        CVT4(a0, a1, a2, a3, w2)
        CVT4(a0, a1, a2, a3, w3)
    }
    for (; p < end; p += 4) {
        int idx = p + g;
        bool valid = idx < end;
        int s = __builtin_nontemporal_load(eidx + (valid ? idx : beg));
        u32 wv = *(const u32*)(hp + (size_t)s * 64 + fb * 4);
        if (valid) { CVT4(a0, a1, a2, a3, wv) }
    }
    a0 += __shfl_xor(a0, 16); a0 += __shfl_xor(a0, 32);
    a1 += __shfl_xor(a1, 16); a1 += __shfl_xor(a1, 32);
    a2 += __shfl_xor(a2, 16); a2 += __shfl_xor(a2, 32);
    a3 += __shfl_xor(a3, 16); a3 += __shfl_xor(a3, 32);
    u32 sv = *(const u32*)(hp + (size_t)w * 64 + fb * 4);
    float dv = dinv[w];
    float v0 = fmaxf(dv * (a0 + __builtin_amdgcn_cvt_f32_fp8((int)sv, 0)) + bias[fb * 4 + 0], 0.f);
    float v1 = fmaxf(dv * (a1 + __builtin_amdgcn_cvt_f32_fp8((int)sv, 1)) + bias[fb * 4 + 1], 0.f);
    float v2 = fmaxf(dv * (a2 + __builtin_amdgcn_cvt_f32_fp8((int)sv, 2)) + bias[fb * 4 + 2], 0.f);
    float v3 = fmaxf(dv * (a3 + __builtin_amdgcn_cvt_f32_fp8((int)sv, 3)) + bias[fb * 4 + 3], 0.f);
    if (g == 0) {
        int r = __builtin_amdgcn_cvt_pk_fp8_f32(v0, v1, 0, false);
        r = __builtin_amdgcn_cvt_pk_fp8_f32(v2, v3, r, true);
        *(u32*)(out + (size_t)w * 64 + fb * 4) = (u32)r;
    }
}

// ---------- layer 2: CSR aggregation fused with graph-mean partials ----------
__global__ __launch_bounds__(256) void agg_csr_reduce_kernel(const u8* __restrict__ hp,
                                                             const int* __restrict__ eidx,
                                                             const int* __restrict__ rowend,
                                                             const float* __restrict__ dinv,
                                                             const float* __restrict__ bias,
                                                             float* __restrict__ partials, int n) {
    __shared__ float sred[256];
    int t = threadIdx.x, lane = t & 63;
    const int g = lane >> 4, fb = lane & 15;
    int wid = (blockIdx.x * 256 + t) >> 6;
    int wstride = gridDim.x * 4;
    float bl0 = bias[fb * 4 + 0], bl1 = bias[fb * 4 + 1];
    float bl2 = bias[fb * 4 + 2], bl3 = bias[fb * 4 + 3];
    float t0 = 0.f, t1 = 0.f, t2 = 0.f, t3 = 0.f;
    for (int w = wid; w < n; w += wstride) {
        int beg = (w & (BK - 1)) ? rowend[w - 1] : (w >> SH) * SLOT;
        int end = rowend[w];
        float a0 = 0.f, a1 = 0.f, a2 = 0.f, a3 = 0.f;
        int p = beg;
        for (; p + 16 <= end; p += 16) {
            int s0 = __builtin_nontemporal_load(eidx + p + g);
            int s1 = __builtin_nontemporal_load(eidx + p + 4 + g);
            int s2 = __builtin_nontemporal_load(eidx + p + 8 + g);
            int s3 = __builtin_nontemporal_load(eidx + p + 12 + g);
            u32 w0 = *(const u32*)(hp + (size_t)s0 * 64 + fb * 4);
            u32 w1 = *(const u32*)(hp + (size_t)s1 * 64 + fb * 4);
            u32 w2 = *(const u32*)(hp + (size_t)s2 * 64 + fb * 4);
            u32 w3 = *(const u32*)(hp + (size_t)s3 * 64 + fb * 4);
            CVT4(a0, a1, a2, a3, w0)
            CVT4(a0, a1, a2, a3, w1)
            CVT4(a0, a1, a2, a3, w2)
            CVT4(a0, a1, a2, a3, w3)
        }
        for (; p < end; p += 4) {
            int idx = p + g;
            bool valid = idx < end;
            int s = __builtin_nontemporal_load(eidx + (valid ? idx : beg));
            u32 wv = *(const u32*)(hp + (size_t)s * 64 + fb * 4);
            if (valid) { CVT4(a0, a1, a2, a3, wv) }
        }
        a0 += __shfl_xor(a0, 16); a0 += __shfl_xor(a0, 32);
        a1 += __shfl_xor(a1, 16); a1 += __shfl_xor(a1, 32);
        a2 += __shfl_xor(a2, 16); a2 += __shfl_xor(a2, 32);
        a3 += __shfl_xor(a3, 16); a3 += __shfl_xor(a3, 32);
        u32 sv = *(const u32*)(hp + (size_t)w * 64 + fb * 4);
        float dv = dinv[w];
        t0 += fmaxf(dv * (a0 + __builtin_amdgcn_cvt_f32_fp8((int)sv, 0)) + bl0, 0.f);
        t1 += fmaxf(dv * (a1 + __builtin_amdgcn_cvt_f32_fp8((int)sv, 1)) + bl1, 0.f);
        t2 += fmaxf(dv * (a2 + __builtin_amdgcn_cvt_f32_fp8((int)sv, 2)) + bl2, 0.f);
        t3 += fmaxf(dv * (a3 + __builtin_amdgcn_cvt_f32_fp8((int)sv, 3)) + bl3, 0.f);
    }
    int wv_ = t >> 6;
    if (g == 0) {
        sred[wv_ * 64 + fb * 4 + 0] = t0;
        sred[wv_ * 64 + fb * 4 + 1] = t1;
        sred[wv_ * 64 + fb * 4 + 2] = t2;
        sred[wv_ * 64 + fb * 4 + 3] = t3;
    }
    __syncthreads();
    if (t < 64) partials[blockIdx.x * 64 + t] = sred[t] + sred[t + 64] + sred[t + 128] + sred[t + 192];
}

// ---------- two-stage partial reduction ----------
__global__ __launch_bounds__(256) void gsum_stage_kernel(const float* __restrict__ parts, int nblk,
                                                         float* __restrict__ gsum) {
    __shared__ float sred[256];
    int t = threadIdx.x, col = t & 63;
    float a = 0.f;
    for (int bk = blockIdx.x * 4 + (t >> 6); bk < nblk; bk += gridDim.x * 4)
        a += parts[bk * 64 + col];
    sred[t] = a; __syncthreads();
    if (t < 64) atomicAdd(&gsum[t], sred[t] + sred[t + 64] + sred[t + 128] + sred[t + 192]);
}

__global__ void final_gsum_kernel(const float* __restrict__ gsum, const float* __restrict__ Wf,
                                  const float* __restrict__ bf_, float* __restrict__ out, float invn) {
    int lane = threadIdx.x;
    float v = gsum[lane] * invn * Wf[lane];
    #pragma unroll
    for (int off = 32; off; off >>= 1) v += __shfl_down(v, off);
    if (lane == 0) out[0] = 1.f / (1.f + expf(-(v + bf_[0])));
}

// ================= fallback (atomic aggregation, fp8 hp, VALU gemm) =================
template <int K, typename TIn>
__global__ __launch_bounds__(256) void gemm_scale_kernel(const TIn* __restrict__ A,
                                                         const float* __restrict__ W,
                                                         const float* __restrict__ dinv,
                                                         u8* __restrict__ out8, int n) {
    __shared__ float xs[16][K];
    const int t = threadIdx.x;
    const int row0 = blockIdx.x * 16;
    if constexpr (sizeof(TIn) == 4) {
        const float* Af = (const float*)A;
        for (int i = t; i < 16 * K; i += 256) {
            int r = i / K;
            (&xs[0][0])[i] = (row0 + r < n) ? Af[(size_t)row0 * K + i] : 0.f;
        }
    } else {
        const u8* Ab = (const u8*)A;
        for (int i = t; i < 16 * K; i += 256) {
            int r = i / K;
            (&xs[0][0])[i] = (row0 + r < n) ? fp82f(Ab[(size_t)row0 * K + i]) : 0.f;
        }
    }
    __syncthreads();
    const int c = t & 63, rg = t >> 6;
    float acc[4] = {0.f, 0.f, 0.f, 0.f};
    #pragma unroll 4
    for (int k = 0; k < K; ++k) {
        float w = W[k * HID + c];
        #pragma unroll
        for (int j = 0; j < 4; ++j) acc[j] += xs[rg + 4 * j][k] * w;
    }
    #pragma unroll
    for (int j = 0; j < 4; ++j) {
        int r = row0 + rg + 4 * j;
        if (r < n) out8[(size_t)r * HID + c] = f2fp8(acc[j] * dinv[r]);
    }
}
__global__ void deg_f_kernel(const int* __restrict__ dst, float* __restrict__ deg, int ne) {
    int i = blockIdx.x * blockDim.x + threadIdx.x, st = gridDim.x * blockDim.x;
    for (; i < ne; i += st) atomicAdd(&deg[dst[i]], 1.0f);
}
__global__ void dinvf_kernel(float* __restrict__ deg, int n) {
    int i = blockIdx.x * blockDim.x + threadIdx.x;
    if (i < n) deg[i] = rsqrtf(deg[i] + 1.0f);
}
__global__ __launch_bounds__(256) void aggregate_atomic_kernel(const u8* __restrict__ hp,
        const int* __restrict__ src, const int* __restrict__ dst,
        const float* __restrict__ dinv, float* __restrict__ outf, int ne) {
    size_t tt = (size_t)blockIdx.x * 256 + threadIdx.x;
    int e = (int)(tt >> 6), f = (int)(tt & 63);
    if (e >= ne) return;
    int s = src[e], d = dst[e];
    atomicAdd(&outf[(size_t)d * HID + f], fp82f(hp[s * HID + f]) * dinv[d]);
}
__global__ void finalize1_fb_kernel(u8* __restrict__ hp, const float* __restrict__ agg,
                                    const float* __restrict__ dinv, const float* __restrict__ b, int n) {
    size_t i = (size_t)blockIdx.x * blockDim.x + threadIdx.x;
    if (i >= (size_t)n * HID) return;
    int node = (int)(i >> 6);
    float v = agg[i] + fp82f(hp[i]) * dinv[node] + b[i & 63];
    hp[i] = f2fp8(fmaxf(v, 0.f));
}
__global__ __launch_bounds__(256) void finalize2_fb_kernel(const u8* __restrict__ hp,
        const float* __restrict__ agg, const float* __restrict__ dinv,
        const float* __restrict__ b, float* __restrict__ gsum, int n) {
    __shared__ float sred[256];
    const int t = threadIdx.x, c = t & 63;
    const size_t total = (size_t)n * HID;
    const size_t stride = (size_t)gridDim.x * blockDim.x;
    float acc = 0.f;
    for (size_t i = (size_t)blockIdx.x * blockDim.x + t; i < total; i += stride) {
        int node = (int)(i >> 6);
        acc += fmaxf(agg[i] + fp82f(hp[i]) * dinv[node] + b[c], 0.f);
    }
    sred[t] = acc; __syncthreads();
    if (t < 64) atomicAdd(&gsum[c], sred[t] + sred[t + 64] + sred[t + 128] + sred[t + 192]);
}
__global__ void final_gsum_fb_kernel(const float* __restrict__ gsum, const float* __restrict__ Wf,
                                     const float* __restrict__ bf_, float* __restrict__ out, int n) {
    int lane = threadIdx.x;
    float v = (gsum[lane] / (float)n) * Wf[lane];
    #pragma unroll
    for (int off = 32; off; off >>= 1) v += __shfl_down(v, off);
    if (lane == 0) out[0] = 1.f / (1.f + expf(-(v + bf_[0])));
}

extern "C" void kernel_launch(void* const* d_in, const int* in_sizes, int n_in,
                              void* d_out, int out_size, void* d_ws, size_t ws_size,
                              hipStream_t stream) {
    const float* x  = (const float*)d_in[0];
    const int*   ei = (const int*)d_in[1];
    const float* W1 = (const float*)d_in[2];
    const float* b1 = (const float*)d_in[3];
    const float* W2 = (const float*)d_in[4];
    const float* b2 = (const float*)d_in[5];
    const float* Wf = (const float*)d_in[6];
    const float* bf_ = (const float*)d_in[7];
    float* out = (float*)d_out;

    const int n  = in_sizes[0] / 256;
    const int ne = in_sizes[1] / 2;
    const int* srcp = ei;
    const int* dstp = ei + ne;
    const int B = (n + BK - 1) / BK;

    // ---- primary layout (bcur and gsum adjacent for one memset) ----
    char* p = (char*)d_ws;
    u32*   ep     = (u32*)p;   p += ((size_t)B * SLOT + 4096) * 4;
    int*   bcur   = (int*)p;   p += BPAD * 4;
    float* gsum   = (float*)p; p += 64 * 4;
    float* dinv   = (float*)p; p += (size_t)n * 4;
    int*   rowend = (int*)p;   p += (size_t)n * 4;
    int*   eidx   = (int*)p;   p += ((size_t)B * SLOT + 4096) * 4;
    float* parts  = (float*)p; p += (size_t)NBLK2 * 64 * 4;
    p = (char*)(((uintptr_t)p + 15) & ~(uintptr_t)15);
    u16*   wpack1 = (u16*)p;   p += 256 * 64 * 2;
    u16*   wpack2 = (u16*)p;   p += 64 * 64 * 2;
    u8*    hp     = (u8*)p;    p += (size_t)n * HID;
    u8*    h1     = (u8*)p;    p += (size_t)n * HID;
    size_t need = (size_t)(p - (char*)d_ws);

    bool slack_ok = ((size_t)ne / (size_t)B) <= (size_t)(SLOT - 1024);

    if (ws_size >= need && n <= (1 << 17) && slack_ok) {
        (void)hipMemsetAsync(bcur, 0, (BPAD + 64) * 4, stream);
        pack_both_kernel<<<80, 256, 0, stream>>>(W1, W2, wpack1, wpack2);

        const int PBLK = (ne + CH - 1) / CH;
        const int ntiles = (n + 15) / 16;
        const int GBLK = (ntiles + 3) / 4;
        mega1_kernel<<<PBLK + GBLK, 256, 0, stream>>>(srcp, dstp, bcur, ep, ne,
                                                      x, wpack1, hp, n, PBLK, GBLK);
        bucket_sort_kernel<<<B, 256, 0, stream>>>(ep, bcur, eidx, rowend, dinv, hp, n);
        agg_csr_kernel<<<(n + 3) / 4, 256, 0, stream>>>(hp, eidx, rowend, dinv, b1, h1, n);
        mfma_gemm2_kernel<<<GBLK, 256, 0, stream>>>(h1, wpack2, dinv, hp, n);
        agg_csr_reduce_kernel<<<NBLK2, 256, 0, stream>>>(hp, eidx, rowend, dinv, b2, parts, n);
        gsum_stage_kernel<<<128, 256, 0, stream>>>(parts, NBLK2, gsum);
        final_gsum_kernel<<<1, 64, 0, stream>>>(gsum, Wf, bf_, out, 1.0f / (float)n);
    } else {
        // ---- fallback: atomic aggregation, fp8 hp, VALU gemm ----
        char* q = (char*)d_ws;
        float* dinvF = (float*)q; q += (size_t)n * 4;
        float* gsumF = (float*)q; q += 64 * 4;
        u8*    hpF   = (u8*)q;   q += (size_t)n * HID;
        float* aggF  = (float*)q;

        (void)hipMemsetAsync(dinvF, 0, ((size_t)n + 64) * 4, stream);
        deg_f_kernel<<<2048, 256, 0, stream>>>(dstp, dinvF, ne);
        dinvf_kernel<<<(n + 255) / 256, 256, 0, stream>>>(dinvF, n);

        gemm_scale_kernel<256, float><<<(n + 15) / 16, 256, 0, stream>>>(x, W1, dinvF, hpF, n);
        (void)hipMemsetAsync(aggF, 0, (size_t)n * HID * 4, stream);
        aggregate_atomic_kernel<<<(int)(((size_t)ne * 64 + 255) / 256), 256, 0, stream>>>(hpF, srcp, dstp, dinvF, aggF, ne);
        finalize1_fb_kernel<<<(int)(((size_t)n * HID + 255) / 256), 256, 0, stream>>>(hpF, aggF, dinvF, b1, n);

        gemm_scale_kernel<64, u8><<<(n + 15) / 16, 256, 0, stream>>>(hpF, W2, dinvF, hpF, n);
        (void)hipMemsetAsync(aggF, 0, (size_t)n * HID * 4, stream);
        aggregate_atomic_kernel<<<(int)(((size_t)ne * 64 + 255) / 256), 256, 0, stream>>>(hpF, srcp, dstp, dinvF, aggF, ne);
        finalize2_fb_kernel<<<2048, 256, 0, stream>>>(hpF, aggF, dinvF, b2, gsumF, n);
        final_gsum_fb_kernel<<<1, 64, 0, stream>>>(gsumF, Wf, bf_, out, n);
    }
}